// Round 2
// baseline (271.426 us; speedup 1.0000x reference)
//
#include <hip/hip_runtime.h>
#include <hip/hip_bf16.h>

#define BB 2
#define SS 2048
#define DD 1024
#define HH 16
#define HD 64

typedef __attribute__((ext_vector_type(8))) short bf16x8;
typedef __attribute__((ext_vector_type(4))) float floatx4;

__device__ __forceinline__ short f2bf(float x) {
  __hip_bfloat16 h = __float2bfloat16(x);
  return __builtin_bit_cast(short, h);
}

// pack two fp32 -> two bf16 (RNE) in one instruction
__device__ __forceinline__ unsigned cvtpk_bf16(float lo, float hi) {
  unsigned r;
  asm("v_cvt_pk_bf16_f32 %0, %1, %2" : "=v"(r) : "v"(lo), "v"(hi));
  return r;
}

// async global->LDS, 16B per lane; LDS dest is wave-uniform base + lane*16
__device__ __forceinline__ void load_lds16(const void* g, void* l) {
  __builtin_amdgcn_global_load_lds(
      (const __attribute__((address_space(1))) unsigned int*)g,
      (__attribute__((address_space(3))) unsigned int*)l, 16, 0, 0);
}

__device__ __forceinline__ float redsum16(float v) {
  v += __shfl_xor(v, 1, 64);
  v += __shfl_xor(v, 2, 64);
  v += __shfl_xor(v, 4, 64);
  v += __shfl_xor(v, 8, 64);
  return v;
}

// ---------------------------------------------------------------------------
// prep: fused conv_in (q,k,v fp32->bf16) + conv_w (Wq/Wk/Wv transpose) +
// conv_wo (Wo transpose). 1D grid 13312, block 256.
// ---------------------------------------------------------------------------
__global__ __launch_bounds__(256) void prep(
    const float* __restrict__ q, const float* __restrict__ k,
    const float* __restrict__ v, const float* __restrict__ Wq,
    const float* __restrict__ Wk, const float* __restrict__ Wv,
    const float* __restrict__ Wo, short* __restrict__ qo,
    short* __restrict__ ko, short* __restrict__ vo, short* __restrict__ qT,
    short* __restrict__ kT, short* __restrict__ vT, short* __restrict__ WoT) {
  __shared__ short sT[64 * 72];
  const int blk = blockIdx.x;
  if (blk < 12288) {
    const int which = blk >> 12, x = blk & 4095;
    const float* src = which == 0 ? q : which == 1 ? k : v;
    short* dst       = which == 0 ? qo : which == 1 ? ko : vo;
    size_t i = ((size_t)x * 256 + threadIdx.x) * 4;
    float4 f = *(const float4*)(src + i);
    short4 s;
    s.x = f2bf(f.x); s.y = f2bf(f.y); s.z = f2bf(f.z); s.w = f2bf(f.w);
    *(short4*)(dst + i) = s;
    return;
  }
  const int t = threadIdx.x, r = t >> 2, c0 = (t & 3) * 16;
  const float* src;
  short* dst;
  if (blk < 13056) {  // conv_w: W[h][1024][64] -> WT[h*64+e][1024]
    const int b2 = blk - 12288, which = b2 >> 8, rr = b2 & 255;
    const int dtile = rr & 15, h = rr >> 4, d0 = dtile * 64;
    const float* W = which == 0 ? Wq : which == 1 ? Wk : Wv;
    short* WT      = which == 0 ? qT : which == 1 ? kT : vT;
    src = W + ((size_t)h * DD + d0 + r) * HD + c0;
    dst = WT + ((size_t)h * HD + r) * DD + d0 + c0;
  } else {  // conv_wo: Wo[1024][1024] -> WoT[n][k]
    const int b3 = blk - 13056;
    const int k0 = (b3 & 15) * 64, n0 = (b3 >> 4) * 64;
    src = Wo + (size_t)(k0 + r) * DD + n0 + c0;
    dst = WoT + (size_t)(n0 + r) * DD + k0 + c0;
  }
  const float4* s4 = (const float4*)src;
  float4 f0 = s4[0], f1 = s4[1], f2 = s4[2], f3 = s4[3];
  const float ff[16] = {f0.x, f0.y, f0.z, f0.w, f1.x, f1.y, f1.z, f1.w,
                        f2.x, f2.y, f2.z, f2.w, f3.x, f3.y, f3.z, f3.w};
#pragma unroll
  for (int j = 0; j < 16; ++j) sT[r * 72 + c0 + j] = f2bf(ff[j]);
  __syncthreads();
  alignas(16) short tmp[16];
#pragma unroll
  for (int j = 0; j < 16; ++j) tmp[j] = sT[(c0 + j) * 72 + r];
  *(int4*)(dst) = *(const int4*)(tmp);
  *(int4*)(dst + 8) = *(const int4*)(tmp + 8);
}

// ---------------------------------------------------------------------------
// Projection GEMM: ph = x @ W, M=4096, N=1024, K=1024. q/k: plain [m][n]
// store. Masked rows of q/k are ZEROED here (score = q.k = 0 exactly ->
// exp2(0)=1 in attn, replacing the per-score pad cndmasks), and q is scaled
// by 1/8 * log2(e) so attn can use raw v_exp_f32 (exp2). v: fused transpose
// epilogue -> vhT[bh][e][s]. 1D grid 768, XCD-decoded.
// ---------------------------------------------------------------------------
__global__ __launch_bounds__(256) void proj(
    const short* __restrict__ xq, const short* __restrict__ xk,
    const short* __restrict__ xv, const short* __restrict__ WqT,
    const short* __restrict__ WkT, const short* __restrict__ WvT,
    const int* __restrict__ mask, short* __restrict__ qh,
    short* __restrict__ kh, short* __restrict__ vhT) {
  __shared__ short sA[128 * 32];
  __shared__ short sB[128 * 32];
  __shared__ short sT2[128 * 136];  // v-transpose staging (16B-aligned rows)
  const int xcd = blockIdx.x & 7, tt = blockIdx.x >> 3;
  const int which = tt >> 5;              // 0..2
  const int rest = tt & 31;
  const int j = ((xcd & 3) << 1) | (rest >> 4);   // n-block 0..7
  const int i = ((xcd >> 2) << 4) | (rest & 15);  // m-block 0..31
  const short* X  = which == 0 ? xq : which == 1 ? xk : xv;
  const short* WT = which == 0 ? WqT : which == 1 ? WkT : WvT;
  const int m0 = i * 128, n0 = j * 128;
  const int tid = threadIdx.x, wid = tid >> 6, lane = tid & 63;
  const int quad = lane >> 4, l16 = lane & 15;
  const int wr = wid >> 1, wc = wid & 1;

  floatx4 acc[4][4] = {};
  for (int k0 = 0; k0 < DD; k0 += 32) {
    __syncthreads();
#pragma unroll
    for (int ii = 0; ii < 2; ++ii) {
      const int c = wid * 2 + ii;
      const int ci = c * 64 + lane;
      load_lds16(X + (size_t)(m0 + (ci >> 2)) * DD + k0 + (ci & 3) * 8,
                 &sA[c * 512]);
      load_lds16(WT + (size_t)(n0 + (ci >> 2)) * DD + k0 + (ci & 3) * 8,
                 &sB[c * 512]);
    }
    __syncthreads();
    bf16x8 af[4], bfr[4];
#pragma unroll
    for (int mi = 0; mi < 4; ++mi)
      af[mi] = *(const bf16x8*)&sA[(wr * 64 + mi * 16 + l16) * 32 + quad * 8];
#pragma unroll
    for (int ni = 0; ni < 4; ++ni)
      bfr[ni] = *(const bf16x8*)&sB[(wc * 64 + ni * 16 + l16) * 32 + quad * 8];
#pragma unroll
    for (int mi = 0; mi < 4; ++mi)
#pragma unroll
      for (int ni = 0; ni < 4; ++ni)
        acc[mi][ni] = __builtin_amdgcn_mfma_f32_16x16x32_bf16(
            af[mi], bfr[ni], acc[mi][ni], 0, 0, 0);
  }
  if (which != 2) {
    short* dst = which == 0 ? qh : kh;
    // q: fold 1/sqrt(64) AND log2(e) (attn uses exp2). k: unit scale.
    const float scale = (which == 0) ? 0.18033688f : 1.0f;
#pragma unroll
    for (int mi = 0; mi < 4; ++mi)
#pragma unroll
      for (int r2 = 0; r2 < 4; ++r2) {
        const int m = m0 + wr * 64 + mi * 16 + quad * 4 + r2;
        const float rs = mask[m] ? 0.f : scale;  // zero masked rows
#pragma unroll
        for (int ni = 0; ni < 4; ++ni) {
          const int n = n0 + wc * 64 + ni * 16 + l16;
          dst[(size_t)m * DD + n] = f2bf(acc[mi][ni][r2] * rs);
        }
      }
  } else {
    // v: transpose 128x128 tile through LDS, store vhT[bh][e][s]
    __syncthreads();
#pragma unroll
    for (int mi = 0; mi < 4; ++mi)
#pragma unroll
      for (int ni = 0; ni < 4; ++ni)
#pragma unroll
        for (int r2 = 0; r2 < 4; ++r2) {
          const int ml = wr * 64 + mi * 16 + quad * 4 + r2;  // s-local
          const int nl = wc * 64 + ni * 16 + l16;            // (h,e)-local
          sT2[nl * 136 + ml] = f2bf(acc[mi][ni][r2]);
        }
    __syncthreads();
    const int b = m0 >> 11;
    const int row = tid >> 1, half = tid & 1;  // row = n-local 0..127
    const int h = (n0 + row) >> 6, e = (n0 + row) & 63;
    short* dstp = vhT + ((size_t)(b * HH + h) * HD + e) * SS + (m0 & 2047) +
                  half * 64;
    const short* srcl = &sT2[row * 136 + half * 64];
#pragma unroll
    for (int jj = 0; jj < 8; ++jj)
      *(int4*)(dstp + jj * 8) = *(const int4*)(srcl + jj * 8);
  }
}

// ---------------------------------------------------------------------------
// Flash attention, bf16 MFMA, deferred softmax (t-additive partials).
// One wave owns one (bh, strip) fully — no cross-wave t-split, no combine,
// ZERO __syncthreads. 2048 strip-tasks -> 512 blocks x 4 waves. All 4 waves
// of a block have the SAME tile count (tasks sorted by size); blocks queued
// heaviest-first -> LPT self-balancing (512 blocks / 256 CUs). Pad masks
// pre-folded into qh/kh (zeroed rows -> score 0 -> exp2(0)=1); per-score
// work = exp2 + add + 0.5*cvt_pk + store. K double-buffered in regs.
// XCD-decoded: bh group {4x..4x+3} on XCD x (K/Vt L2-resident per XCD).
// ---------------------------------------------------------------------------
__global__ __launch_bounds__(256, 2) void attn(
    const short* __restrict__ qh, const short* __restrict__ kh,
    const short* __restrict__ vhT, short* __restrict__ X) {
  __shared__ short sP[4][32 * 72];  // per-wave P tile, padded stride 72
  const int tid = threadIdx.x, wid = tid >> 6, lane = tid & 63;
  const int quad = lane >> 4, l16 = lane & 15;
  const int xcd = blockIdx.x & 7, rank = blockIdx.x >> 3;  // rank 0..63
  const int task = rank * 4 + wid;    // 0..255 within XCD
  const int szc = task >> 3;          // size class 0..31 -> ntiles = 32-szc
  const int mm = task & 7;
  const int bh = (xcd << 2) | (mm >> 1);
  const int strip = 63 - 2 * szc - (mm & 1);
  const int b = bh >> 4, h = bh & 15;
  const int row0 = strip * 32;
  const int ntiles = 32 - szc;  // == (row0>>6)+1, causal extent

  const short* Q  = qh + (size_t)b * SS * DD + h * HD;
  const short* K  = kh + (size_t)b * SS * DD + h * HD;
  const short* Vt = vhT + (size_t)bh * HD * SS;
  short* sPw = sP[wid];

  // Q fragments: A-layout, m = l16 (row row0+mi*16+l16), k = ks*32+quad*8
  bf16x8 aq[2][2];
#pragma unroll
  for (int mi = 0; mi < 2; ++mi)
#pragma unroll
    for (int ks = 0; ks < 2; ++ks)
      aq[mi][ks] = *(const bf16x8*)(Q + (size_t)(row0 + mi * 16 + l16) * DD +
                                    ks * 32 + quad * 8);

  floatx4 o[2][4] = {};
  float lacc[2][4] = {};

  bf16x8 bkA[4][2], bkB[4][2];
#pragma unroll
  for (int ni = 0; ni < 4; ++ni)
#pragma unroll
    for (int ks = 0; ks < 2; ++ks)
      bkA[ni][ks] = *(const bf16x8*)(K + (size_t)(ni * 16 + l16) * DD +
                                     ks * 32 + quad * 8);

  auto step = [&](int tb, bf16x8 (&bkc)[4][2], bf16x8 (&bkn)[4][2]) {
    const int t0 = tb * 64;
    // V loads for this tile issue first: latency hides under QK + softmax
    bf16x8 bv[4][2];
#pragma unroll
    for (int ei = 0; ei < 4; ++ei)
#pragma unroll
      for (int ks = 0; ks < 2; ++ks)
        bv[ei][ks] = *(const bf16x8*)(Vt + (size_t)(ei * 16 + l16) * SS + t0 +
                                      ks * 32 + quad * 8);
    // prefetch next tile's K into the other register buffer
    if (tb + 1 < ntiles) {
#pragma unroll
      for (int ni = 0; ni < 4; ++ni)
#pragma unroll
        for (int ks = 0; ks < 2; ++ks)
          bkn[ni][ks] =
              *(const bf16x8*)(K + (size_t)(t0 + 64 + ni * 16 + l16) * DD +
                               ks * 32 + quad * 8);
    }
    const bool diag = (tb == ntiles - 1);  // wave-uniform
#pragma unroll
    for (int mi = 0; mi < 2; ++mi) {
      floatx4 s[4] = {};
#pragma unroll
      for (int ks = 0; ks < 2; ++ks)
#pragma unroll
        for (int ni = 0; ni < 4; ++ni)
          s[ni] = __builtin_amdgcn_mfma_f32_16x16x32_bf16(
              aq[mi][ks], bkc[ni][ks], s[ni], 0, 0, 0);
#pragma unroll
      for (int ni = 0; ni < 4; ++ni)
#pragma unroll
        for (int r2p = 0; r2p < 2; ++r2p) {
          // pads pre-zeroed in proj -> s=0 -> exp2(0)=1 exactly
          float p0 = __builtin_amdgcn_exp2f(s[ni][2 * r2p]);
          float p1 = __builtin_amdgcn_exp2f(s[ni][2 * r2p + 1]);
          if (diag) {  // causal wins over pad
            const int row = row0 + mi * 16 + quad * 4 + 2 * r2p;
            const int col = t0 + ni * 16 + l16;
            if (col > row) p0 = 0.f;
            if (col > row + 1) p1 = 0.f;
          }
          lacc[mi][2 * r2p] += p0;
          lacc[mi][2 * r2p + 1] += p1;
          const unsigned pk = cvtpk_bf16(p0, p1);
          short* wp = &sPw[(mi * 16 + quad * 4 + 2 * r2p) * 72 + ni * 16 + l16];
          wp[0] = (short)pk;           // ds_write_b16
          wp[72] = (short)(pk >> 16);  // ds_write_b16_d16_hi
        }
    }
    // O += P V : P via per-wave LDS round-trip (A-layout)
#pragma unroll
    for (int ks = 0; ks < 2; ++ks) {
      bf16x8 ap[2];
#pragma unroll
      for (int mi = 0; mi < 2; ++mi)
        ap[mi] = *(const bf16x8*)&sPw[(mi * 16 + l16) * 72 + ks * 32 +
                                      quad * 8];
#pragma unroll
      for (int mi = 0; mi < 2; ++mi)
#pragma unroll
        for (int ei = 0; ei < 4; ++ei)
          o[mi][ei] = __builtin_amdgcn_mfma_f32_16x16x32_bf16(
              ap[mi], bv[ei][ks], o[mi][ei], 0, 0, 0);
    }
  };

  int tb = 0;
  for (;;) {  // 2x unrolled ping-pong over K register buffers
    step(tb, bkA, bkB);
    if (++tb >= ntiles) break;
    step(tb, bkB, bkA);
    if (++tb >= ntiles) break;
  }

  // per-wave epilogue: denominator reduce over l16 group, scale, store
#pragma unroll
  for (int mi = 0; mi < 2; ++mi)
#pragma unroll
    for (int r2 = 0; r2 < 4; ++r2) {
      const float inv = 1.0f / redsum16(lacc[mi][r2]);
      const int srow = row0 + mi * 16 + quad * 4 + r2;
#pragma unroll
      for (int ei = 0; ei < 4; ++ei)
        X[((size_t)bh * SS + srow) * HD + ei * 16 + l16] =
            f2bf(o[mi][ei][r2] * inv);
    }
}

// ---------------------------------------------------------------------------
// out = X[4096,1024] @ Wo, via WoT[n][k]. BM=128 BN=64 BK=32, 256 threads.
// grid (32, 16) = 512 blocks (2/CU). fp32 output.
// ---------------------------------------------------------------------------
__global__ __launch_bounds__(256) void oproj(const short* __restrict__ X,
                                             const short* __restrict__ WoT,
                                             float* __restrict__ out) {
  __shared__ short sA[128 * 32];
  __shared__ short sB[64 * 32];
  const int m0 = blockIdx.x * 128, n0 = blockIdx.y * 64;
  const int tid = threadIdx.x, wid = tid >> 6, lane = tid & 63;
  const int quad = lane >> 4, l16 = lane & 15;
  const int wr = wid >> 1, wc = wid & 1;

  floatx4 acc[4][2] = {};
  for (int k0 = 0; k0 < DD; k0 += 32) {
    __syncthreads();
#pragma unroll
    for (int i = 0; i < 2; ++i) {
      const int c = wid * 2 + i;
      const int ci = c * 64 + lane;
      load_lds16(X + (size_t)(m0 + (ci >> 2)) * DD + k0 + (ci & 3) * 8,
                 &sA[c * 512]);
    }
    {
      const int ci = wid * 64 + lane;
      load_lds16(WoT + (size_t)(n0 + (ci >> 2)) * DD + k0 + (ci & 3) * 8,
                 &sB[wid * 512]);
    }
    __syncthreads();
    bf16x8 af[4], bfr[2];
#pragma unroll
    for (int mi = 0; mi < 4; ++mi)
      af[mi] = *(const bf16x8*)&sA[(wr * 64 + mi * 16 + l16) * 32 + quad * 8];
#pragma unroll
    for (int ni = 0; ni < 2; ++ni)
      bfr[ni] = *(const bf16x8*)&sB[(wc * 32 + ni * 16 + l16) * 32 + quad * 8];
#pragma unroll
    for (int mi = 0; mi < 4; ++mi)
#pragma unroll
      for (int ni = 0; ni < 2; ++ni)
        acc[mi][ni] = __builtin_amdgcn_mfma_f32_16x16x32_bf16(
            af[mi], bfr[ni], acc[mi][ni], 0, 0, 0);
  }
#pragma unroll
  for (int mi = 0; mi < 4; ++mi)
#pragma unroll
    for (int ni = 0; ni < 2; ++ni)
#pragma unroll
      for (int r2 = 0; r2 < 4; ++r2)
        out[(size_t)(m0 + wr * 64 + mi * 16 + quad * 4 + r2) * DD + n0 +
            wc * 32 + ni * 16 + l16] = acc[mi][ni][r2];
}

// ---------------------------------------------------------------------------
extern "C" void kernel_launch(void* const* d_in, const int* in_sizes, int n_in,
                              void* d_out, int out_size, void* d_ws,
                              size_t ws_size, hipStream_t stream) {
  const float* q  = (const float*)d_in[0];
  const float* k  = (const float*)d_in[1];
  const float* v  = (const float*)d_in[2];
  const float* Wq = (const float*)d_in[3];
  const float* Wk = (const float*)d_in[4];
  const float* Wv = (const float*)d_in[5];
  const float* Wo = (const float*)d_in[6];
  const int* mask = (const int*)d_in[7];
  float* out = (float*)d_out;

  // workspace layout (shorts); X aliases qb (dead after proj). vhT has its
  // OWN region (kb is still live while proj writes vhT).
  short* ws = (short*)d_ws;
  const size_t NIN = (size_t)BB * SS * DD;  // 4,194,304
  const size_t NWH = (size_t)HH * HD * DD;  // 1,048,576
  short* qb  = ws;        // also X
  short* kb  = ws + NIN;
  short* vb  = ws + 2 * NIN;
  short* WqT = ws + 3 * NIN;
  short* WkT = WqT + NWH;
  short* WvT = WkT + NWH;
  short* WoT = WvT + NWH;
  short* qhp = WoT + (size_t)DD * DD;
  short* khp = qhp + NIN;
  short* vhT = khp + NIN;
  short* Xp  = qb;

  prep<<<dim3(13312), 256, 0, stream>>>(q, k, v, Wq, Wk, Wv, Wo, qb, kb, vb,
                                        WqT, WkT, WvT, WoT);
  proj<<<dim3(768), 256, 0, stream>>>(qb, kb, vb, WqT, WkT, WvT, mask, qhp,
                                      khp, vhT);
  attn<<<dim3(512), 256, 0, stream>>>(qhp, khp, vhT, Xp);
  oproj<<<dim3(32, 16), 256, 0, stream>>>(Xp, WoT, out);
}